// Round 3
// baseline (1304.027 us; speedup 1.0000x reference)
//
#include <hip/hip_runtime.h>
#include <stdint.h>

#define NQ   8192
#define NB   2
#define KNN  10
#define K1   11                 // keep 11 incl. self; drop min (self) at the end
#define NTOT (NB * NQ)
#define IDXMASK 0x1FFFu

#define G      32
#define NCELLS (G * G * G)
#define GRID_MIN (-4.5f)
#define CELL_S  (9.0f / (float)G)     // 0.28125
#define INV_S   ((float)G / 9.0f)

static __device__ __forceinline__ uint32_t umin32(uint32_t a, uint32_t b) { return a < b ? a : b; }
static __device__ __forceinline__ uint32_t umax32(uint32_t a, uint32_t b) { return a > b ? a : b; }

static __device__ __forceinline__ int cellCoord(float v) {
    int c = (int)floorf((v - GRID_MIN) * INV_S);
    return min(max(c, 0), G - 1);
}

// ---------------- count ----------------
__global__ __launch_bounds__(256) void grid_count(
    const float* __restrict__ p1, uint32_t* __restrict__ counts)
{
    const int t = blockIdx.x * 256 + threadIdx.x;   // 0..NTOT-1
    const int b = t >> 13, i = t & (NQ - 1);
    const float* P = p1 + (size_t)b * NQ * 3 + (size_t)i * 3;
    const int cx = cellCoord(P[0]), cy = cellCoord(P[1]), cz = cellCoord(P[2]);
    const uint32_t cid = (uint32_t)b * NCELLS + ((uint32_t)(cz * G + cy) * G + cx);
    atomicAdd(&counts[cid], 1u);
}

// ---------------- exclusive scan over 2*NCELLS counts (one block) ----------------
__global__ __launch_bounds__(1024) void grid_scan(
    const uint32_t* __restrict__ counts, uint32_t* __restrict__ offs)
{
    __shared__ uint32_t part[1024];
    const int tid = threadIdx.x;
    const int base = tid * 64;                       // 1024*64 = 65536 = 2*NCELLS
    uint32_t s = 0;
#pragma unroll 8
    for (int k = 0; k < 64; ++k) s += counts[base + k];
    part[tid] = s;
    __syncthreads();
    if (tid == 0) {
        uint32_t run = 0;
        for (int i = 0; i < 1024; ++i) { uint32_t v = part[i]; part[i] = run; run += v; }
    }
    __syncthreads();
    uint32_t run = part[tid];
#pragma unroll 8
    for (int k = 0; k < 64; ++k) { offs[base + k] = run; run += counts[base + k]; }
    if (tid == 1023) offs[2 * NCELLS] = run;         // == NTOT
}

// ---------------- scatter points into binned array ----------------
__global__ __launch_bounds__(256) void grid_scatter(
    const float* __restrict__ p1, const uint32_t* __restrict__ offs,
    uint32_t* __restrict__ cursors, float4* __restrict__ binned)
{
    const int t = blockIdx.x * 256 + threadIdx.x;
    const int b = t >> 13, i = t & (NQ - 1);
    const float* P = p1 + (size_t)b * NQ * 3 + (size_t)i * 3;
    const float x = P[0], y = P[1], z = P[2];
    const int cx = cellCoord(x), cy = cellCoord(y), cz = cellCoord(z);
    const uint32_t cid = (uint32_t)b * NCELLS + ((uint32_t)(cz * G + cy) * G + cx);
    const uint32_t pos = offs[cid] + atomicAdd(&cursors[cid], 1u);
    binned[pos] = make_float4(x, y, z, __uint_as_float((uint32_t)i));
}

// ---------------- query (4 lanes per query) + Laplacian L1 loss ----------------
__global__ __launch_bounds__(256) void knn_query_loss(
    const float* __restrict__ p1, const float* __restrict__ p2,
    const uint32_t* __restrict__ offs, const float4* __restrict__ binned,
    float* __restrict__ out)
{
    __shared__ uint32_t smem[64 * 4 * K1];           // 64 queries/block * 44 keys
    const int t    = blockIdx.x * 256 + threadIdx.x; // 0 .. NTOT*4-1
    const int slot = t >> 2;                         // binned slot (spatially sorted)
    const int m    = t & 3;
    const int b    = slot >> 13;                     // batches contiguous in binned[]

    const float4 q4 = binned[slot];
    const float qx = q4.x, qy = q4.y, qz = q4.z;
    const uint32_t qi = __float_as_uint(q4.w);

    const int cx = cellCoord(qx), cy = cellCoord(qy), cz = cellCoord(qz);
    const int rmax = max(max(max(cx, G - 1 - cx), max(cy, G - 1 - cy)),
                         max(cz, G - 1 - cz));
    const uint32_t cellbase = (uint32_t)b * NCELLS;

    uint32_t l[K1];
#pragma unroll
    for (int s = 0; s < K1; ++s) l[s] = 0xFFFFFFFFu;

    bool done = false;
    for (int r = 0; r < G; ++r) {
        if (!done) {
            const int z0 = max(cz - r, 0), z1 = min(cz + r, G - 1);
            const int y0 = max(cy - r, 0), y1 = min(cy + r, G - 1);
            const int x0 = max(cx - r, 0), x1 = min(cx + r, G - 1);
            int cidx = 0;
            for (int z = z0; z <= z1; ++z) {
                const int az = abs(z - cz);
                for (int y = y0; y <= y1; ++y) {
                    const int ay = max(az, abs(y - cy));
                    for (int x = x0; x <= x1; ++x) {
                        const int ch = max(ay, abs(x - cx));
                        if (ch != r) continue;                 // ring shell only
                        if ((cidx++ & 3) != m) continue;       // round-robin to 4 lanes
                        const uint32_t cid = cellbase + ((uint32_t)(z * G + y) * G + x);
                        const uint32_t i0 = offs[cid], i1 = offs[cid + 1];
                        for (uint32_t i = i0; i < i1; ++i) {
                            const float4 c = binned[i];
                            const float dx = qx - c.x, dy = qy - c.y, dz = qz - c.z;
                            const float d  = fmaf(dx, dx, fmaf(dy, dy, dz * dz));
                            uint32_t key = (__float_as_uint(d) & ~IDXMASK) | __float_as_uint(c.w);
#pragma unroll
                            for (int s = 0; s < K1; ++s) {
                                const uint32_t mm = l[s];
                                l[s] = umin32(key, mm);
                                key  = umax32(key, mm);
                            }
                        }
                    }
                }
            }
            // termination: any candidate in ring >= r+1 has dist >= (r*s)^2
            const float br = (float)r * CELL_S;
            const uint32_t Bkey = __float_as_uint(br * br) & ~IDXMASK;
            int cnt = 0;
#pragma unroll
            for (int s = 0; s < K1; ++s) cnt += (l[s] < Bkey) ? 1 : 0;
            cnt += __shfl_xor(cnt, 1, 64);
            cnt += __shfl_xor(cnt, 2, 64);
            done = (cnt >= K1) || (r >= rmax);
        }
        if (__all(done)) break;
    }

    // merge the 4 partial lists through LDS
    const int ql = threadIdx.x >> 2;                 // query-local 0..63
    uint32_t* my = &smem[(ql * 4 + m) * K1];
#pragma unroll
    for (int s = 0; s < K1; ++s) my[s] = l[s];
    __syncthreads();

    float acc = 0.f;
    if (m == 0) {
        const uint32_t* qs = &smem[ql * 4 * K1];
#pragma unroll 4
        for (int e = K1; e < 4 * K1; ++e) {
            uint32_t k = qs[e];
#pragma unroll
            for (int s = 0; s < K1; ++s) {
                const uint32_t mm = l[s];
                l[s] = umin32(k, mm);
                k    = umax32(k, mm);
            }
        }
        // l[0] = self (d=0); neighbors l[1..10]
        const float* __restrict__ P1 = p1 + (size_t)b * NQ * 3;
        const float* __restrict__ P2 = p2 + (size_t)b * NQ * 3;
        float s1x = 0.f, s1y = 0.f, s1z = 0.f, s2x = 0.f, s2y = 0.f, s2z = 0.f;
#pragma unroll
        for (int s = 1; s < K1; ++s) {
            const int n = (int)(l[s] & IDXMASK);
            s1x += P1[n * 3 + 0]; s1y += P1[n * 3 + 1]; s1z += P1[n * 3 + 2];
            s2x += P2[n * 3 + 0]; s2y += P2[n * 3 + 1]; s2z += P2[n * 3 + 2];
        }
        const float invk = 1.0f / (float)KNN;
        const float lx = (s1x * invk - qx) - (s2x * invk - P2[qi * 3 + 0]);
        const float ly = (s1y * invk - qy) - (s2y * invk - P2[qi * 3 + 1]);
        const float lz = (s1z * invk - qz) - (s2z * invk - P2[qi * 3 + 2]);
        acc = fabsf(lx) + fabsf(ly) + fabsf(lz);
    }

#pragma unroll
    for (int off = 32; off > 0; off >>= 1)
        acc += __shfl_down(acc, off, 64);
    if ((threadIdx.x & 63) == 0) {
        const float scale = 1.0f / (float)(NTOT * 3);
        atomicAdd(out, acc * scale);
    }
}

extern "C" void kernel_launch(void* const* d_in, const int* in_sizes, int n_in,
                              void* d_out, int out_size, void* d_ws, size_t ws_size,
                              hipStream_t stream) {
    const float* p1 = (const float*)d_in[0];
    const float* p2 = (const float*)d_in[1];
    float* out      = (float*)d_out;

    // ws layout
    uint32_t* counts  = (uint32_t*)d_ws;                            // 256 KB
    uint32_t* cursors = (uint32_t*)((char*)d_ws + (size_t)NB * NCELLS * 4);   // 256 KB
    uint32_t* offs    = (uint32_t*)((char*)d_ws + (size_t)2 * NB * NCELLS * 4); // 256 KB + 4
    float4*   binned  = (float4*)((char*)d_ws + (size_t)1024 * 1024);          // 256 KB

    hipMemsetAsync(d_out, 0, sizeof(float), stream);
    hipMemsetAsync(d_ws, 0, (size_t)2 * NB * NCELLS * 4, stream);   // counts + cursors

    grid_count  <<<dim3(NTOT / 256), 256, 0, stream>>>(p1, counts);
    grid_scan   <<<dim3(1), 1024, 0, stream>>>(counts, offs);
    grid_scatter<<<dim3(NTOT / 256), 256, 0, stream>>>(p1, offs, cursors, binned);
    knn_query_loss<<<dim3(NTOT * 4 / 256), 256, 0, stream>>>(p1, p2, offs, binned, out);
}

// Round 4
// 1288.047 us; speedup vs baseline: 1.0124x; 1.0124x over previous
//
#include <hip/hip_runtime.h>
#include <stdint.h>

#define NQ   8192
#define NB   2
#define KNN  10
#define K1   11                  // keep 11 incl. self (d=0, global min); drop at end
#define NTOT (NB * NQ)
#define IDXMASK 0x1FFFu

#define G      32
#define NCELLS (G * G * G)       // 32768
#define NC2    (NB * NCELLS)     // 65536
#define GRID_MIN (-4.5f)
#define CELL_S  (9.0f / (float)G)
#define INV_S   ((float)G / 9.0f)

#define QW   16                  // waves per query-group block
#define QBLK (QW * 64)           // 1024 threads

static __device__ __forceinline__ uint32_t umin32(uint32_t a, uint32_t b) { return a < b ? a : b; }
static __device__ __forceinline__ uint32_t umax32(uint32_t a, uint32_t b) { return a > b ? a : b; }

static __device__ __forceinline__ int cellCoord(float v) {
    int c = (int)floorf((v - GRID_MIN) * INV_S);
    return min(max(c, 0), G - 1);
}
static __device__ __forceinline__ uint32_t spread3(uint32_t x) {
    x &= 0x3FF;
    x = (x | (x << 16)) & 0x030000FF;
    x = (x | (x << 8))  & 0x0300F00F;
    x = (x | (x << 4))  & 0x030C30C3;
    x = (x | (x << 2))  & 0x09249249;
    return x;
}
static __device__ __forceinline__ void insert11(uint32_t (&l)[K1], uint32_t key) {
#pragma unroll
    for (int s = 0; s < K1; ++s) { const uint32_t m = l[s]; l[s] = umin32(key, m); key = umax32(key, m); }
}

// ---------------- build: count both binnings ----------------
__global__ __launch_bounds__(256) void build_count(
    const float* __restrict__ p1, uint32_t* __restrict__ cntL, uint32_t* __restrict__ cntM)
{
    const int t = blockIdx.x * 256 + threadIdx.x;
    const int b = t >> 13, i = t & (NQ - 1);
    const float* P = p1 + (size_t)b * NQ * 3 + (size_t)i * 3;
    const int cx = cellCoord(P[0]), cy = cellCoord(P[1]), cz = cellCoord(P[2]);
    const uint32_t lin = (uint32_t)b * NCELLS + ((uint32_t)(cz * G + cy) * G + cx);
    const uint32_t mor = (uint32_t)b * NCELLS + (spread3(cx) | (spread3(cy) << 1) | (spread3(cz) << 2));
    atomicAdd(&cntL[lin], 1u);
    atomicAdd(&cntM[mor], 1u);
}

// ---------------- build: exclusive scan (block 0 -> linear, block 1 -> morton) ----------------
__global__ __launch_bounds__(1024) void build_scan(
    const uint32_t* __restrict__ cntL, uint32_t* __restrict__ offL,
    const uint32_t* __restrict__ cntM, uint32_t* __restrict__ offM)
{
    const uint32_t* __restrict__ cnt = blockIdx.x ? cntM : cntL;
    uint32_t* __restrict__ off = blockIdx.x ? offM : offL;
    __shared__ uint32_t part[1024];
    const int tid = threadIdx.x;
    const int base = tid * 64;                        // 1024*64 = 65536
    uint32_t s = 0;
#pragma unroll 8
    for (int k = 0; k < 64; ++k) s += cnt[base + k];
    part[tid] = s;
    __syncthreads();
    // Hillis-Steele inclusive scan over 1024 partials
    for (int d = 1; d < 1024; d <<= 1) {
        uint32_t v = part[tid];
        uint32_t a = (tid >= d) ? part[tid - d] : 0u;
        __syncthreads();
        part[tid] = v + a;
        __syncthreads();
    }
    uint32_t run = tid ? part[tid - 1] : 0u;
#pragma unroll 8
    for (int k = 0; k < 64; ++k) { off[base + k] = run; run += cnt[base + k]; }
    if (tid == 1023) off[NC2] = run;
}

// ---------------- build: scatter into both binned arrays ----------------
__global__ __launch_bounds__(256) void build_scatter(
    const float* __restrict__ p1,
    const uint32_t* __restrict__ offL, uint32_t* __restrict__ curL, float4* __restrict__ binL,
    const uint32_t* __restrict__ offM, uint32_t* __restrict__ curM, float4* __restrict__ binM)
{
    const int t = blockIdx.x * 256 + threadIdx.x;
    const int b = t >> 13, i = t & (NQ - 1);
    const float* P = p1 + (size_t)b * NQ * 3 + (size_t)i * 3;
    const float x = P[0], y = P[1], z = P[2];
    const int cx = cellCoord(x), cy = cellCoord(y), cz = cellCoord(z);
    const uint32_t lin = (uint32_t)b * NCELLS + ((uint32_t)(cz * G + cy) * G + cx);
    const uint32_t mor = (uint32_t)b * NCELLS + (spread3(cx) | (spread3(cy) << 1) | (spread3(cz) << 2));
    const float4 v = make_float4(x, y, z, __uint_as_float((uint32_t)i));
    binL[offL[lin] + atomicAdd(&curL[lin], 1u)] = v;
    binM[offM[mor] + atomicAdd(&curM[mor], 1u)] = v;
}

// ---------------- candidate range scan (wave-uniform i0/i1, 1-deep prefetch) ----------------
static __device__ __forceinline__ void scan_range(
    uint32_t i0, uint32_t i1, const float4* __restrict__ binL,
    float qx, float qy, float qz, uint32_t (&l)[K1])
{
    if (i0 >= i1) return;
    float4 c = binL[i0];
    for (uint32_t i = i0; i < i1; ++i) {
        const float4 nx = binL[umin32(i + 1, i1 - 1)];   // prefetch next
        const float dx = qx - c.x, dy = qy - c.y, dz = qz - c.z;
        const float d  = fmaf(dx, dx, fmaf(dy, dy, dz * dz));
        const uint32_t key = (__float_as_uint(d) & ~IDXMASK) | __float_as_uint(c.w);
        insert11(l, key);
        c = nx;
    }
}

// ---------------- query + loss: one block per 64 Morton-ordered queries ----------------
__global__ __launch_bounds__(QBLK) void knn_query_loss(
    const float* __restrict__ p1, const float* __restrict__ p2,
    const uint32_t* __restrict__ offL, const float4* __restrict__ binL,
    const float4* __restrict__ binM, float* __restrict__ out)
{
    __shared__ uint32_t skeys[64 * QW * K1];   // 45056 B
    __shared__ uint32_t scnt[QBLK];            // 4096 B
    const int lane  = threadIdx.x & 63;
    const int wave  = threadIdx.x >> 6;
    const int group = blockIdx.x;              // 0..255 (<=127: batch 0)
    const int b     = group >> 7;
    const float4 q4 = binM[group * 64 + lane];
    const float qx = q4.x, qy = q4.y, qz = q4.z;
    const uint32_t qi = __float_as_uint(q4.w);

    int cx = cellCoord(qx), cy = cellCoord(qy), cz = cellCoord(qz);
    int bx0 = cx, bx1 = cx, by0 = cy, by1 = cy, bz0 = cz, bz1 = cz;
#pragma unroll
    for (int off = 32; off; off >>= 1) {
        bx0 = min(bx0, __shfl_xor(bx0, off, 64)); bx1 = max(bx1, __shfl_xor(bx1, off, 64));
        by0 = min(by0, __shfl_xor(by0, off, 64)); by1 = max(by1, __shfl_xor(by1, off, 64));
        bz0 = min(bz0, __shfl_xor(bz0, off, 64)); bz1 = max(bz1, __shfl_xor(bz1, off, 64));
    }
    bx0 = __builtin_amdgcn_readfirstlane(bx0); bx1 = __builtin_amdgcn_readfirstlane(bx1);
    by0 = __builtin_amdgcn_readfirstlane(by0); by1 = __builtin_amdgcn_readfirstlane(by1);
    bz0 = __builtin_amdgcn_readfirstlane(bz0); bz1 = __builtin_amdgcn_readfirstlane(bz1);
    const int rmax = max(max(max(bx1, G - 1 - bx0), max(by1, G - 1 - by0)),
                         max(bz1, G - 1 - bz0));
    const uint32_t cellbase = (uint32_t)b * NCELLS;

    uint32_t l[K1];
#pragma unroll
    for (int s = 0; s < K1; ++s) l[s] = 0xFFFFFFFFu;

    bool finished = false;
    for (int r = 0; r < G && !finished; ++r) {
        int rowcnt = 0;
        const int z0 = max(bz0 - r, 0), z1 = min(bz1 + r, G - 1);
        const int y0 = max(by0 - r, 0), y1 = min(by1 + r, G - 1);
        const int x0 = max(bx0 - r, 0), x1 = min(bx1 + r, G - 1);
        for (int z = z0; z <= z1; ++z) {
            const bool zf = (z == bz0 - r) || (z == bz1 + r);
            for (int y = y0; y <= y1; ++y) {
                const bool yf = (y == by0 - r) || (y == by1 + r);
                const uint32_t rowb = cellbase + (uint32_t)(z * G + y) * G;
                if (r == 0 || zf || yf) {
                    if ((rowcnt++ & (QW - 1)) == wave)
                        scan_range(offL[rowb + x0], offL[rowb + x1 + 1], binL, qx, qy, qz, l);
                } else {
                    const int xa = bx0 - r;
                    if (xa >= 0) { if ((rowcnt++ & (QW - 1)) == wave)
                        scan_range(offL[rowb + xa], offL[rowb + xa + 1], binL, qx, qy, qz, l); }
                    const int xb = bx1 + r;
                    if (xb <= G - 1) { if ((rowcnt++ & (QW - 1)) == wave)
                        scan_range(offL[rowb + xb], offL[rowb + xb + 1], binL, qx, qy, qz, l); }
                }
            }
        }
        // termination: unscanned points are >= r*CELL_S from every query in the box
        const float br = (float)r * CELL_S;
        const uint32_t bkey = __float_as_uint(br * br) & ~IDXMASK;
        int c = 0;
#pragma unroll
        for (int s = 0; s < K1; ++s) c += (l[s] < bkey) ? 1 : 0;
        scnt[threadIdx.x] = (uint32_t)c;
        __syncthreads();
        int tot = 0;
#pragma unroll
        for (int w = 0; w < QW; ++w) tot += (int)scnt[w * 64 + lane];
        const bool mydone = (tot >= K1) || (r >= rmax);
        finished = __all(mydone);                 // identical across all waves
        __syncthreads();
    }

    // write partial lists, then log2(QW) tree merge in LDS
    {
        uint32_t* my = &skeys[(lane * QW + wave) * K1];
#pragma unroll
        for (int s = 0; s < K1; ++s) my[s] = l[s];
    }
    for (int st = 1; st < QW; st <<= 1) {
        __syncthreads();
        if (wave < (QW / (2 * st))) {
            const int basei = wave * 2 * st;
            uint32_t* A = &skeys[(lane * QW + basei) * K1];
            const uint32_t* B = &skeys[(lane * QW + basei + st) * K1];
            uint32_t L[K1];
#pragma unroll
            for (int s = 0; s < K1; ++s) L[s] = A[s];
#pragma unroll
            for (int e = 0; e < K1; ++e) insert11(L, B[e]);
#pragma unroll
            for (int s = 0; s < K1; ++s) A[s] = L[s];
        }
    }
    __syncthreads();

    float acc = 0.f;
    if (wave == 0) {
        const uint32_t* L0 = &skeys[lane * QW * K1];
        const float* __restrict__ P1 = p1 + (size_t)b * NQ * 3;
        const float* __restrict__ P2 = p2 + (size_t)b * NQ * 3;
        float s1x = 0.f, s1y = 0.f, s1z = 0.f, s2x = 0.f, s2y = 0.f, s2z = 0.f;
#pragma unroll
        for (int s = 1; s < K1; ++s) {             // L0[0] = self (d = 0)
            const int n = (int)(L0[s] & IDXMASK);
            s1x += P1[n * 3 + 0]; s1y += P1[n * 3 + 1]; s1z += P1[n * 3 + 2];
            s2x += P2[n * 3 + 0]; s2y += P2[n * 3 + 1]; s2z += P2[n * 3 + 2];
        }
        const float invk = 1.0f / (float)KNN;
        const float lx = (s1x * invk - qx) - (s2x * invk - P2[qi * 3 + 0]);
        const float ly = (s1y * invk - qy) - (s2y * invk - P2[qi * 3 + 1]);
        const float lz = (s1z * invk - qz) - (s2z * invk - P2[qi * 3 + 2]);
        acc = fabsf(lx) + fabsf(ly) + fabsf(lz);
#pragma unroll
        for (int off = 32; off > 0; off >>= 1)
            acc += __shfl_down(acc, off, 64);
        if (lane == 0) atomicAdd(out, acc * (1.0f / (float)(NTOT * 3)));
    }
}

extern "C" void kernel_launch(void* const* d_in, const int* in_sizes, int n_in,
                              void* d_out, int out_size, void* d_ws, size_t ws_size,
                              hipStream_t stream) {
    const float* p1 = (const float*)d_in[0];
    const float* p2 = (const float*)d_in[1];
    float* out      = (float*)d_out;

    // workspace layout (~2.1 MB; ws proven >= 23.9 MB in round 2)
    float4*   binL = (float4*)d_ws;                    // 256 KB
    float4*   binM = binL + NTOT;                      // 256 KB
    uint32_t* cntL = (uint32_t*)(binM + NTOT);         // 256 KB
    uint32_t* cntM = cntL + NC2;                       // 256 KB
    uint32_t* curL = cntM + NC2;                       // 256 KB
    uint32_t* curM = curL + NC2;                       // 256 KB
    uint32_t* offL = curM + NC2;                       // 256 KB + 4
    uint32_t* offM = offL + (NC2 + 1);                 // 256 KB + 4

    hipMemsetAsync(d_out, 0, sizeof(float), stream);
    hipMemsetAsync((void*)cntL, 0, (size_t)4 * NC2 * 4, stream);  // cnt/cur L+M

    build_count  <<<dim3(NTOT / 256), 256, 0, stream>>>(p1, cntL, cntM);
    build_scan   <<<dim3(2), 1024, 0, stream>>>(cntL, offL, cntM, offM);
    build_scatter<<<dim3(NTOT / 256), 256, 0, stream>>>(p1, offL, curL, binL, offM, curM, binM);
    knn_query_loss<<<dim3(NTOT / 64), QBLK, 0, stream>>>(p1, p2, offL, binL, binM, out);
}

// Round 5
// 172.335 us; speedup vs baseline: 7.5668x; 7.4741x over previous
//
#include <hip/hip_runtime.h>
#include <stdint.h>

#define NQ   8192
#define NB   2
#define KNN  10
#define K1   11                 // top-11 incl. self (dist 0 = global min key); dropped at end
#define NTOT (NB * NQ)
#define IDXMASK 0x1FFFu

#define NW   16                 // waves per block (1024 threads); block owns 64 queries
#define CAP  24                 // collect capacity per (query, wave-cell); λ≈5.5
#define SUBM 8                  // subsample stride (1024 subsample points per batch)

#define SUB_PER_WAVE  (NQ / SUBM / NW)   // 64
#define CAND_PER_WAVE (NQ / NW)          // 512

// LDS word index for collect/partial-list cells: lane-major => 2-way banks only
#define CK(s, c, lane) (((s) * NW + (c)) * 64 + (lane))

static __device__ __forceinline__ uint32_t umin32(uint32_t a, uint32_t b) { return a < b ? a : b; }
static __device__ __forceinline__ uint32_t umax32(uint32_t a, uint32_t b) { return a > b ? a : b; }

static __device__ __forceinline__ void insert11(uint32_t (&l)[K1], uint32_t key) {
#pragma unroll
    for (int s = 0; s < K1; ++s) {
        const uint32_t m = l[s];
        l[s] = umin32(key, m);
        key  = umax32(key, m);
    }
}

// One block = 64 queries (lane = query), 16 waves split the candidate set.
// Phase 1: subsample (1/8) top-11 -> per-query threshold tau (>= true 10-NN key).
// Phase 2: full scan, collect keys <= tau into LDS cells (exact redo on overflow).
// Phase 3: tree-merge cells -> exact top-11 -> Laplacian L1 loss.
__global__ __launch_bounds__(1024, 4) void plap_knn_loss(
    const float* __restrict__ p1, const float* __restrict__ p2,
    float* __restrict__ out)
{
    __shared__ uint32_t ckeys[CAP * NW * 64];   // 98304 B (phase-1 lists alias here)
    __shared__ uint32_t scnt[NW * 64];          // 4096 B
    __shared__ uint32_t stau[64];               // 256 B

    const int lane = threadIdx.x & 63;
    const int wave = threadIdx.x >> 6;
    const int wq   = __builtin_amdgcn_readfirstlane(wave);  // compiler-uniform wave id
    const int b    = blockIdx.x >> 7;                       // 128 blocks per batch
    const int qi   = ((blockIdx.x & 127) << 6) | lane;      // query index in batch

    const float* __restrict__ P = p1 + (size_t)b * NQ * 3;
    const float qx = P[qi * 3 + 0];
    const float qy = P[qi * 3 + 1];
    const float qz = P[qi * 3 + 2];

    // ---------------- phase 1: subsample top-11 ----------------
    {
        uint32_t l[K1];
#pragma unroll
        for (int s = 0; s < K1; ++s) l[s] = 0xFFFFFFFFu;

        int j = wq * SUB_PER_WAVE * SUBM;                  // uniform (SALU)
        const float* __restrict__ cand = P + (size_t)j * 3;
#pragma unroll 4
        for (int t = 0; t < SUB_PER_WAVE; ++t) {
            const float cx = cand[0], cy = cand[1], cz = cand[2];  // uniform -> s_load
            cand += SUBM * 3;
            const float dx = qx - cx, dy = qy - cy, dz = qz - cz;
            const float d  = fmaf(dx, dx, fmaf(dy, dy, dz * dz));
            const uint32_t key = (__float_as_uint(d) & ~IDXMASK) | (uint32_t)j;
            insert11(l, key);
            j += SUBM;
        }
#pragma unroll
        for (int s = 0; s < K1; ++s) ckeys[CK(s, wq, lane)] = l[s];
    }
    __syncthreads();

    // tree-merge 16 partial lists -> tau = 11th-smallest subsample key
    for (int st = 1; st < NW; st <<= 1) {
        if ((wq & (2 * st - 1)) == 0) {
            uint32_t A[K1];
#pragma unroll
            for (int s = 0; s < K1; ++s) A[s] = ckeys[CK(s, wq, lane)];
#pragma unroll
            for (int e = 0; e < K1; ++e) insert11(A, ckeys[CK(e, wq + st, lane)]);
            if (2 * st < NW) {
#pragma unroll
                for (int s = 0; s < K1; ++s) ckeys[CK(s, wq, lane)] = A[s];
            } else {
                stau[lane] = A[K1 - 1];                     // 11th smallest
            }
        }
        __syncthreads();
    }
    const uint32_t tau = stau[lane];

    // ---------------- phase 2: filter + collect ----------------
    {
        uint32_t cnt = 0;
        bool ovf = false;
        int j = wq * CAND_PER_WAVE;                         // uniform
        const float* __restrict__ cand = P + (size_t)j * 3;
#pragma unroll 4
        for (int t = 0; t < CAND_PER_WAVE; ++t) {
            const float cx = cand[0], cy = cand[1], cz = cand[2];  // uniform -> s_load
            cand += 3;
            const float dx = qx - cx, dy = qy - cy, dz = qz - cz;
            const float d  = fmaf(dx, dx, fmaf(dy, dy, dz * dz));
            const uint32_t tr = __float_as_uint(d) & ~IDXMASK;
            if (tr <= tau) {                               // inclusive: superset of top-11
                if (cnt < CAP) { ckeys[CK(cnt, wq, lane)] = tr | (uint32_t)j; ++cnt; }
                else ovf = true;
            }
            ++j;
        }
        if (__any(ovf)) {
            // exact per-cell redo (deterministic, ~never taken): full insert-chain scan
            uint32_t L[K1];
#pragma unroll
            for (int s = 0; s < K1; ++s) L[s] = 0xFFFFFFFFu;
            int jj = wq * CAND_PER_WAVE;
            const float* __restrict__ cp = P + (size_t)jj * 3;
            for (int t = 0; t < CAND_PER_WAVE; ++t) {
                const float cx = cp[0], cy = cp[1], cz = cp[2];
                cp += 3;
                const float dx = qx - cx, dy = qy - cy, dz = qz - cz;
                const float d  = fmaf(dx, dx, fmaf(dy, dy, dz * dz));
                insert11(L, (__float_as_uint(d) & ~IDXMASK) | (uint32_t)jj);
                ++jj;
            }
#pragma unroll
            for (int s = 0; s < K1; ++s) ckeys[CK(s, wq, lane)] = L[s];
            cnt = K1;
        }
        scnt[wq * 64 + lane] = cnt;
    }
    __syncthreads();

    // ---------------- phase 3: tree-merge cells -> exact top-11 ----------------
    uint32_t F[K1];
#pragma unroll
    for (int s = 0; s < K1; ++s) F[s] = 0xFFFFFFFFu;

    for (int st = 1; st < NW; st <<= 1) {
        if ((wq & (2 * st - 1)) == 0) {
            if (st == 1) {
                const uint32_t ca = scnt[wq * 64 + lane];
                for (uint32_t e = 0; e < ca; ++e) insert11(F, ckeys[CK(e, wq, lane)]);
                const uint32_t cb = scnt[(wq + 1) * 64 + lane];
                for (uint32_t e = 0; e < cb; ++e) insert11(F, ckeys[CK(e, wq + 1, lane)]);
            } else {
#pragma unroll
                for (int e = 0; e < K1; ++e) insert11(F, ckeys[CK(e, wq + st, lane)]);
            }
        }
        __syncthreads();
        if ((wq & (2 * st - 1)) == 0 && 2 * st < NW) {
#pragma unroll
            for (int s = 0; s < K1; ++s) ckeys[CK(s, wq, lane)] = F[s];
        }
        __syncthreads();
    }

    // ---------------- loss (wave 0 only; F[0] = self) ----------------
    if (wq == 0) {
        const float* __restrict__ P2 = p2 + (size_t)b * NQ * 3;
        float s1x = 0.f, s1y = 0.f, s1z = 0.f, s2x = 0.f, s2y = 0.f, s2z = 0.f;
#pragma unroll
        for (int s = 1; s < K1; ++s) {
            const int n = (int)(F[s] & IDXMASK);
            s1x += P[n * 3 + 0];  s1y += P[n * 3 + 1];  s1z += P[n * 3 + 2];
            s2x += P2[n * 3 + 0]; s2y += P2[n * 3 + 1]; s2z += P2[n * 3 + 2];
        }
        const float invk = 1.0f / (float)KNN;
        const float lx = (s1x * invk - qx) - (s2x * invk - P2[qi * 3 + 0]);
        const float ly = (s1y * invk - qy) - (s2y * invk - P2[qi * 3 + 1]);
        const float lz = (s1z * invk - qz) - (s2z * invk - P2[qi * 3 + 2]);
        float acc = fabsf(lx) + fabsf(ly) + fabsf(lz);
#pragma unroll
        for (int off = 32; off > 0; off >>= 1)
            acc += __shfl_down(acc, off, 64);
        if (lane == 0) atomicAdd(out, acc * (1.0f / (float)(NTOT * 3)));
    }
}

extern "C" void kernel_launch(void* const* d_in, const int* in_sizes, int n_in,
                              void* d_out, int out_size, void* d_ws, size_t ws_size,
                              hipStream_t stream) {
    const float* p1 = (const float*)d_in[0];
    const float* p2 = (const float*)d_in[1];
    float* out      = (float*)d_out;

    hipMemsetAsync(d_out, 0, sizeof(float), stream);
    plap_knn_loss<<<dim3(NTOT / 64), dim3(NW * 64), 0, stream>>>(p1, p2, out);
}

// Round 6
// 153.528 us; speedup vs baseline: 8.4937x; 1.1225x over previous
//
#include <hip/hip_runtime.h>
#include <stdint.h>

#define NQ   8192
#define NB   2
#define KNN  10
#define K1   11                 // top-11 incl. self (dist 0 = global min key); dropped at end
#define NTOT (NB * NQ)
#define IDXMASK 0x1FFFu

#define NW    16                // waves per block (1024 threads); block owns 64 queries
#define NHALF 2                 // candidate set split across 2 blocks per query-group
#define HCAND (NQ / NHALF)      // 4096 candidates per block
#define CPW   (HCAND / NW)      // 256 candidates per wave
#define CAP   18                // collect capacity per (query, wave) cell; lambda ~5.5
#define SUBM  8                 // subsample stride -> 512-point sample per half

// LDS word index, lane-major: 2-way bank aliasing only (free)
#define CK(s, c, lane) (((s) * NW + (c)) * 64 + (lane))

static __device__ __forceinline__ uint32_t umin32(uint32_t a, uint32_t b) { return a < b ? a : b; }
static __device__ __forceinline__ uint32_t umax32(uint32_t a, uint32_t b) { return a > b ? a : b; }

static __device__ __forceinline__ void insert11(uint32_t (&l)[K1], uint32_t key) {
#pragma unroll
    for (int s = 0; s < K1; ++s) {
        const uint32_t m = l[s];
        l[s] = umin32(key, m);
        key  = umax32(key, m);
    }
}

// One block = 64 queries (lane = query) x half the candidate set (16 waves split it).
// Phase 1: subsample top-11 -> tau (>= true 11th key). Phase 2: branch-free filter
// collect. Phase 3: block tree-merge -> half-exact top-11 -> global partial.
__global__ __launch_bounds__(1024, 8) void plap_knn_partial(
    const float* __restrict__ p1, uint32_t* __restrict__ part)
{
    __shared__ uint32_t ckeys[CAP * NW * 64];   // 73728 B
    __shared__ uint32_t scnt[NW * 64];          // 4096 B
    __shared__ uint32_t stau[64];               // 256 B -> 78080 B total (2 blocks/CU)

    const int lane  = threadIdx.x & 63;
    const int wave  = threadIdx.x >> 6;
    const int wq    = __builtin_amdgcn_readfirstlane(wave);
    const int group = blockIdx.x >> 1;          // 0..255
    const int half  = blockIdx.x & 1;
    const int b     = group >> 7;
    const int qi    = ((group & 127) << 6) | lane;   // query index in batch
    const int qidG  = group * 64 + lane;             // global query id

    const float* __restrict__ P = p1 + (size_t)b * NQ * 3;
    const float qx = P[qi * 3 + 0];
    const float qy = P[qi * 3 + 1];
    const float qz = P[qi * 3 + 2];

    const int j0 = half * HCAND + wq * CPW;     // wave's candidate range base (uniform)

    // ---------------- phase 1: subsample top-11 -> tau ----------------
    {
        uint32_t l[K1];
#pragma unroll
        for (int s = 0; s < K1; ++s) l[s] = 0xFFFFFFFFu;
        const float* __restrict__ cand = P + (size_t)j0 * 3;
        int j = j0;
#pragma unroll 4
        for (int t = 0; t < CPW / SUBM; ++t) {  // 32 samples per wave
            const float cx = cand[0], cy = cand[1], cz = cand[2];
            cand += SUBM * 3;
            const float dx = qx - cx, dy = qy - cy, dz = qz - cz;
            const float d  = fmaf(dx, dx, fmaf(dy, dy, dz * dz));
            insert11(l, (__float_as_uint(d) & ~IDXMASK) | (uint32_t)j);
            j += SUBM;
        }
#pragma unroll
        for (int s = 0; s < K1; ++s) ckeys[CK(s, wq, lane)] = l[s];
    }
    __syncthreads();

    for (int st = 1; st < NW; st <<= 1) {       // tree-merge -> 11th of 512 sample
        if ((wq & (2 * st - 1)) == 0) {
            uint32_t A[K1];
#pragma unroll
            for (int s = 0; s < K1; ++s) A[s] = ckeys[CK(s, wq, lane)];
#pragma unroll
            for (int e = 0; e < K1; ++e) insert11(A, ckeys[CK(e, wq + st, lane)]);
            if (2 * st < NW) {
#pragma unroll
                for (int s = 0; s < K1; ++s) ckeys[CK(s, wq, lane)] = A[s];
            } else {
                stau[lane] = A[K1 - 1];
            }
        }
        __syncthreads();
    }
    const uint32_t tau  = stau[lane];
    const float    tauF = __uint_as_float(tau);     // positive floats: uint order == float order

    // ---------------- phase 2: branch-free filter + collect ----------------
    {
        uint32_t cnt = 0;
        const float* __restrict__ cand = P + (size_t)j0 * 3;
        int j = j0;
#pragma unroll 4
        for (int t = 0; t < CPW; ++t) {
            const float cx = cand[0], cy = cand[1], cz = cand[2];
            cand += 3;
            const float dx = qx - cx, dy = qy - cy, dz = qz - cz;
            const float d  = fmaf(dx, dx, fmaf(dy, dy, dz * dz));
            const uint32_t key = (__float_as_uint(d) & ~IDXMASK) | (uint32_t)j;
            ckeys[CK(umin32(cnt, CAP - 1), wq, lane)] = key;   // unconditional store
            cnt += (d <= tauF) ? 1u : 0u;                      // commit iff passer
            ++j;
        }
        if (__any(cnt >= CAP)) {
            // exact fallback for this wave (P ~ 1e-5/cell): full insert-chain redo
            uint32_t L[K1];
#pragma unroll
            for (int s = 0; s < K1; ++s) L[s] = 0xFFFFFFFFu;
            const float* __restrict__ cp = P + (size_t)j0 * 3;
            int jj = j0;
            for (int t = 0; t < CPW; ++t) {
                const float cx = cp[0], cy = cp[1], cz = cp[2];
                cp += 3;
                const float dx = qx - cx, dy = qy - cy, dz = qz - cz;
                const float d  = fmaf(dx, dx, fmaf(dy, dy, dz * dz));
                insert11(L, (__float_as_uint(d) & ~IDXMASK) | (uint32_t)jj);
                ++jj;
            }
#pragma unroll
            for (int s = 0; s < K1; ++s) ckeys[CK(s, wq, lane)] = L[s];
            cnt = K1;
        }
        scnt[wq * 64 + lane] = cnt;
    }
    __syncthreads();

    // ---------------- phase 3: tree-merge cells -> half-exact top-11 ----------------
    uint32_t F[K1];
#pragma unroll
    for (int s = 0; s < K1; ++s) F[s] = 0xFFFFFFFFu;

    for (int st = 1; st < NW; st <<= 1) {
        if ((wq & (2 * st - 1)) == 0) {
            if (st == 1) {
                const uint32_t ca = scnt[wq * 64 + lane];
                for (uint32_t e = 0; e < ca; ++e) insert11(F, ckeys[CK(e, wq, lane)]);
                const uint32_t cb = scnt[(wq + 1) * 64 + lane];
                for (uint32_t e = 0; e < cb; ++e) insert11(F, ckeys[CK(e, wq + 1, lane)]);
            } else {
#pragma unroll
                for (int e = 0; e < K1; ++e) insert11(F, ckeys[CK(e, wq + st, lane)]);
            }
        }
        __syncthreads();
        if ((wq & (2 * st - 1)) == 0 && 2 * st < NW) {
#pragma unroll
            for (int s = 0; s < K1; ++s) ckeys[CK(s, wq, lane)] = F[s];
        }
        __syncthreads();
    }

    if (wq == 0) {
        // layout [half][s][qidG]: coalesced here and in the merge kernel
#pragma unroll
        for (int s = 0; s < K1; ++s)
            part[((size_t)half * K1 + s) * NTOT + qidG] = F[s];
    }
}

// Merge the two half-partials per query -> exact top-11 -> Laplacian L1 loss.
__global__ __launch_bounds__(256) void plap_merge_loss(
    const float* __restrict__ p1, const float* __restrict__ p2,
    const uint32_t* __restrict__ part, float* __restrict__ out)
{
    const int qid = blockIdx.x * 256 + threadIdx.x;   // 0..NTOT-1
    const int b   = qid >> 13;
    const int qi  = qid & (NQ - 1);
    const float* __restrict__ P1 = p1 + (size_t)b * NQ * 3;
    const float* __restrict__ P2 = p2 + (size_t)b * NQ * 3;

    uint32_t F[K1];
#pragma unroll
    for (int s = 0; s < K1; ++s) F[s] = part[(size_t)s * NTOT + qid];
#pragma unroll
    for (int s = 0; s < K1; ++s) insert11(F, part[((size_t)K1 + s) * NTOT + qid]);

    float s1x = 0.f, s1y = 0.f, s1z = 0.f, s2x = 0.f, s2y = 0.f, s2z = 0.f;
#pragma unroll
    for (int s = 1; s < K1; ++s) {                    // F[0] = self (d = 0)
        const int n = (int)(F[s] & IDXMASK);
        s1x += P1[n * 3 + 0]; s1y += P1[n * 3 + 1]; s1z += P1[n * 3 + 2];
        s2x += P2[n * 3 + 0]; s2y += P2[n * 3 + 1]; s2z += P2[n * 3 + 2];
    }
    const float invk = 1.0f / (float)KNN;
    const float lx = (s1x * invk - P1[qi * 3 + 0]) - (s2x * invk - P2[qi * 3 + 0]);
    const float ly = (s1y * invk - P1[qi * 3 + 1]) - (s2y * invk - P2[qi * 3 + 1]);
    const float lz = (s1z * invk - P1[qi * 3 + 2]) - (s2z * invk - P2[qi * 3 + 2]);
    float acc = fabsf(lx) + fabsf(ly) + fabsf(lz);

#pragma unroll
    for (int off = 32; off > 0; off >>= 1)
        acc += __shfl_down(acc, off, 64);
    if ((threadIdx.x & 63) == 0)
        atomicAdd(out, acc * (1.0f / (float)(NTOT * 3)));
}

extern "C" void kernel_launch(void* const* d_in, const int* in_sizes, int n_in,
                              void* d_out, int out_size, void* d_ws, size_t ws_size,
                              hipStream_t stream) {
    const float* p1 = (const float*)d_in[0];
    const float* p2 = (const float*)d_in[1];
    float* out      = (float*)d_out;
    uint32_t* part  = (uint32_t*)d_ws;   // 2 * 11 * 16384 * 4 B = 1.44 MB

    hipMemsetAsync(d_out, 0, sizeof(float), stream);
    plap_knn_partial<<<dim3(NTOT / 64 * NHALF), dim3(NW * 64), 0, stream>>>(p1, part);
    plap_merge_loss<<<dim3(NTOT / 256), dim3(256), 0, stream>>>(p1, p2, part, out);
}